// Round 1
// baseline (221.977 us; speedup 1.0000x reference)
//
#include <hip/hip_runtime.h>
#include <cstddef>
#include <cstdint>

// Problem constants (fixed by reference file)
#define B_    256
#define V_    128000
#define T_    16
#define TOPK_ 100
#define TPB   1024
#define CAP   4096
#define NF4   (V_ / 4)    // 32000 float4 per row
#define NHIST 4096

// Two-phase decomposition
#define SEG    8                   // segments per row
#define CAPSEG 512                 // candidate capacity per segment
#define SEGF4  (NF4 / SEG)         // 4000 float4 per segment
#define TPB1   256                 // collect block size -> 32 waves/CU at 2048 blocks
#define TPB2   512                 // select block size
#define T0     0.996f              // speculative threshold (~512 cand/row expected)

#define WS_CAND_BYTES ((size_t)B_ * SEG * CAPSEG * sizeof(float))   // 4 MiB
#define WS_CNT_BYTES  ((size_t)B_ * SEG * sizeof(int))              // 8 KiB
#define WS_NEED       (WS_CAND_BYTES + WS_CNT_BYTES)

__global__ void zero_out_kernel(float* o) {
    o[0] = 0.f; o[1] = 0.f; o[2] = 0.f;
}

// ---------------------------------------------------------------------------
// Phase 1: full-occupancy streaming scan. 8 blocks per row, each owns a
// contiguous 64 KB segment. Candidates >= T0 (excluding target columns) are
// staged in LDS and written contiguously to the workspace with a raw count
// (count > CAPSEG signals overflow -> select kernel falls back).
// ---------------------------------------------------------------------------
__global__ __launch_bounds__(TPB1) void collect_kernel(
        const float* __restrict__ sparse,
        const int*   __restrict__ tids,
        float*       __restrict__ cand,   // [B][SEG][CAPSEG]
        int*         __restrict__ cnt,    // [B][SEG]
        float*       __restrict__ out) {
    __shared__ float s_vals[CAPSEG];
    __shared__ int   s_ids[T_];
    __shared__ int   s_cnt;

    const int gb  = blockIdx.x;
    const int row = gb >> 3;         // gb / SEG
    const int seg = gb & 7;          // gb % SEG
    const int tid = threadIdx.x;

    // zero the output accumulators (stream-ordered before select_kernel)
    if (gb == 0 && tid < 3) out[tid] = 0.f;

    if (tid < T_) s_ids[tid] = tids[row * T_ + tid];
    if (tid == 0) s_cnt = 0;
    __syncthreads();

    const float4* __restrict__ rp4 =
        (const float4*)(sparse + (size_t)row * V_);
    const int base = seg * SEGF4;
    const int end  = base + SEGF4;

    for (int i = base + tid; i < end; i += TPB1) {
        float4 v = rp4[i];
        // fast reject: one branch per 16 B, body taken ~1.6% of the time
        float mx = fmaxf(fmaxf(v.x, v.y), fmaxf(v.z, v.w));
        if (mx >= T0) {
            int col = i << 2;
            float xs[4] = {v.x, v.y, v.z, v.w};
            #pragma unroll
            for (int c = 0; c < 4; ++c) {
                float x = xs[c];
                if (x >= T0) {
                    int cc = col + c;
                    bool is_t = false;
                    #pragma unroll
                    for (int j = 0; j < T_; ++j) is_t |= (cc == s_ids[j]);
                    if (!is_t) {
                        int k = atomicAdd(&s_cnt, 1);
                        if (k < CAPSEG) s_vals[k] = x;
                    }
                }
            }
        }
    }
    __syncthreads();

    int lc = s_cnt;
    int w  = min(lc, CAPSEG);
    float* __restrict__ dst = cand + (size_t)gb * CAPSEG;
    for (int i = tid; i < w; i += TPB1) dst[i] = s_vals[i];
    if (tid == 0) cnt[gb] = lc;      // raw (unclamped) -> overflow detectable
}

// ---------------------------------------------------------------------------
// Phase 2: per-row select. Gathers the ~512 precollected candidates, bitonic
// sorts, sums top-100. Computes target/margin losses (16 gathers, L3-hot).
// Exact histogram fallback (full rescan) if the speculative pass failed.
// ---------------------------------------------------------------------------
__global__ __launch_bounds__(TPB2) void select_kernel(
        const float* __restrict__ sparse,
        const int*   __restrict__ tids,
        const float* __restrict__ cand,
        const int*   __restrict__ cnt,
        float*       __restrict__ out) {
    __shared__ float    s_cand[CAP];
    __shared__ unsigned s_hist[NHIST];
    __shared__ int      s_ids[T_];
    __shared__ int      s_scnt[SEG];
    __shared__ int      s_off[SEG + 1];
    __shared__ int      s_flag;
    __shared__ int      s_cnt2;
    __shared__ int      s_bstar;
    __shared__ float    s_red[128];

    const int row = blockIdx.x;
    const int tid = threadIdx.x;
    const float* __restrict__ rp = sparse + (size_t)row * V_;

    if (tid < T_) s_ids[tid] = tids[row * T_ + tid];
    __syncthreads();

    // ---- target loss + margin loss (threads 0..15, one gather each) ----
    if (tid < T_) {
        float x  = rp[s_ids[tid]];
        float tl = -logf(x + 1e-8f);
        float ml = fmaxf(1.0f - x, 0.0f);
        #pragma unroll
        for (int off = 8; off > 0; off >>= 1) {
            tl += __shfl_down(tl, off);
            ml += __shfl_down(ml, off);
        }
        if (tid == 0) {
            atomicAdd(out + 0, tl * (1.0f / (B_ * T_)));
            atomicAdd(out + 1, ml * (1.0f / (B_ * T_)));
        }
    }

    // ---- gather per-segment counts, prefix sum, validate ----
    if (tid == 0) {
        int acc = 0, bad = 0;
        #pragma unroll
        for (int s = 0; s < SEG; ++s) {
            int c = cnt[row * SEG + s];
            bad |= (c > CAPSEG);
            int cc = min(c, CAPSEG);
            s_scnt[s] = cc;
            s_off[s]  = acc;
            acc += cc;
        }
        s_off[SEG] = acc;
        s_flag = bad || (acc < TOPK_) || (acc > CAP);
    }
    __syncthreads();

    int cntv;
    if (!s_flag) {
        // ---- gather candidates into contiguous LDS ----
        cntv = s_off[SEG];
        #pragma unroll
        for (int s = 0; s < SEG; ++s) {
            int len = s_scnt[s];
            const float* __restrict__ src =
                cand + (size_t)(row * SEG + s) * CAPSEG;
            float* __restrict__ dstp = s_cand + s_off[s];
            for (int i = tid; i < len; i += TPB2) dstp[i] = src[i];
        }
        __syncthreads();
    } else {
        // ---- exact fallback: histogram over the full row (proven path) ----
        for (int i = tid; i < NHIST; i += TPB2) s_hist[i] = 0u;
        if (tid == 0) s_cnt2 = 0;
        __syncthreads();
        const float4* rp4 = (const float4*)rp;
        for (int i = tid; i < NF4; i += TPB2) {
            float4 v = rp4[i];
            float xs[4] = {v.x, v.y, v.z, v.w};
            #pragma unroll
            for (int c = 0; c < 4; ++c) {
                int b = (int)(xs[c] * (float)NHIST);
                b = min(max(b, 0), NHIST - 1);
                atomicAdd(&s_hist[b], 1u);
            }
        }
        __syncthreads();
        if (tid == 0) {
            for (int j = 0; j < T_; ++j) {
                int id = s_ids[j];
                bool dup = false;
                for (int q = 0; q < j; ++q) dup = dup || (s_ids[q] == id);
                if (!dup) {
                    int b = (int)(rp[id] * (float)NHIST);
                    b = min(max(b, 0), NHIST - 1);
                    s_hist[b]--;
                }
            }
            int acc = 0, b = NHIST - 1;
            for (; b >= 0; --b) {
                acc += (int)s_hist[b];
                if (acc >= TOPK_) break;
            }
            s_bstar = max(b, 0);
        }
        __syncthreads();
        int bstar = s_bstar;
        for (int i = tid; i < NF4; i += TPB2) {
            float4 v = rp4[i];
            int col = i << 2;
            float xs[4] = {v.x, v.y, v.z, v.w};
            #pragma unroll
            for (int c = 0; c < 4; ++c) {
                float x = xs[c];
                int b2 = (int)(x * (float)NHIST);
                b2 = min(max(b2, 0), NHIST - 1);
                if (b2 >= bstar) {
                    int cc = col + c;
                    bool is_t = false;
                    #pragma unroll
                    for (int j = 0; j < T_; ++j) is_t |= (cc == s_ids[j]);
                    if (!is_t) {
                        int k = atomicAdd(&s_cnt2, 1);
                        if (k < CAP) s_cand[k] = x;
                    }
                }
            }
        }
        __syncthreads();
        cntv = min(s_cnt2, CAP);
    }

    // ---- pad to pow2 and bitonic sort ascending (pads = -inf -> at front) ----
    int n2 = 128;
    while (n2 < cntv) n2 <<= 1;          // n2 <= CAP (pow2)
    for (int i = cntv + tid; i < n2; i += TPB2) s_cand[i] = -1e30f;
    __syncthreads();

    for (int k = 2; k <= n2; k <<= 1) {
        for (int j = k >> 1; j > 0; j >>= 1) {
            for (int i = tid; i < n2; i += TPB2) {
                int p = i ^ j;
                if (p > i) {
                    float a = s_cand[i], b = s_cand[p];
                    bool asc = ((i & k) == 0);
                    if (asc ? (a > b) : (a < b)) {
                        s_cand[i] = b; s_cand[p] = a;
                    }
                }
            }
            __syncthreads();
        }
    }

    // ---- sum the top-100 (largest at the tail after ascending sort) ----
    if (tid < 128) {
        float v = (tid < TOPK_) ? s_cand[n2 - 1 - tid] : 0.f;
        s_red[tid] = v;
    }
    __syncthreads();
    #pragma unroll
    for (int off = 64; off > 0; off >>= 1) {
        if (tid < off) s_red[tid] += s_red[tid + off];
        __syncthreads();
    }
    if (tid == 0) atomicAdd(out + 2, s_red[0] * (1.0f / (B_ * TOPK_)));
}

// ---------------------------------------------------------------------------
// Fallback single-kernel path (previous proven kernel) used only if the
// workspace is too small for the two-phase plan.
// ---------------------------------------------------------------------------
__global__ __launch_bounds__(TPB) void row_kernel(
        const float* __restrict__ sparse,
        const int*   __restrict__ tids,
        float*       __restrict__ out) {
    __shared__ float    s_cand[CAP];
    __shared__ unsigned s_hist[NHIST];
    __shared__ int      s_ids[T_];
    __shared__ int      s_cnt;
    __shared__ int      s_bstar;
    __shared__ float    s_red[128];

    const int row = blockIdx.x;
    const int tid = threadIdx.x;
    const float* __restrict__ rp = sparse + (size_t)row * V_;

    if (tid < T_) s_ids[tid] = tids[row * T_ + tid];
    if (tid == 0) s_cnt = 0;
    __syncthreads();

    if (tid < T_) {
        float x  = rp[s_ids[tid]];
        float tl = -logf(x + 1e-8f);
        float ml = fmaxf(1.0f - x, 0.0f);
        #pragma unroll
        for (int off = 8; off > 0; off >>= 1) {
            tl += __shfl_down(tl, off);
            ml += __shfl_down(ml, off);
        }
        if (tid == 0) {
            atomicAdd(out + 0, tl * (1.0f / (B_ * T_)));
            atomicAdd(out + 1, ml * (1.0f / (B_ * T_)));
        }
    }

    const float4* rp4 = (const float4*)rp;
    for (int i = tid; i < NF4; i += TPB) {
        float4 v = rp4[i];
        int col = i << 2;
        float xs[4] = {v.x, v.y, v.z, v.w};
        #pragma unroll
        for (int c = 0; c < 4; ++c) {
            float x = xs[c];
            if (x >= T0) {
                int cc = col + c;
                bool is_t = false;
                #pragma unroll
                for (int j = 0; j < T_; ++j) is_t |= (cc == s_ids[j]);
                if (!is_t) {
                    int k = atomicAdd(&s_cnt, 1);
                    if (k < CAP) s_cand[k] = x;
                }
            }
        }
    }
    __syncthreads();

    int cnt = s_cnt;
    if (cnt < TOPK_ || cnt > CAP) {
        for (int i = tid; i < NHIST; i += TPB) s_hist[i] = 0u;
        __syncthreads();
        for (int i = tid; i < NF4; i += TPB) {
            float4 v = rp4[i];
            float xs[4] = {v.x, v.y, v.z, v.w};
            #pragma unroll
            for (int c = 0; c < 4; ++c) {
                int b = (int)(xs[c] * (float)NHIST);
                b = min(max(b, 0), NHIST - 1);
                atomicAdd(&s_hist[b], 1u);
            }
        }
        __syncthreads();
        if (tid == 0) {
            for (int j = 0; j < T_; ++j) {
                int id = s_ids[j];
                bool dup = false;
                for (int q = 0; q < j; ++q) dup = dup || (s_ids[q] == id);
                if (!dup) {
                    int b = (int)(rp[id] * (float)NHIST);
                    b = min(max(b, 0), NHIST - 1);
                    s_hist[b]--;
                }
            }
            int acc = 0, b = NHIST - 1;
            for (; b >= 0; --b) {
                acc += (int)s_hist[b];
                if (acc >= TOPK_) break;
            }
            s_bstar = max(b, 0);
            s_cnt = 0;
        }
        __syncthreads();
        int bstar = s_bstar;
        for (int i = tid; i < NF4; i += TPB) {
            float4 v = rp4[i];
            int col = i << 2;
            float xs[4] = {v.x, v.y, v.z, v.w};
            #pragma unroll
            for (int c = 0; c < 4; ++c) {
                float x = xs[c];
                int b = (int)(x * (float)NHIST);
                b = min(max(b, 0), NHIST - 1);
                if (b >= bstar) {
                    int cc = col + c;
                    bool is_t = false;
                    #pragma unroll
                    for (int j = 0; j < T_; ++j) is_t |= (cc == s_ids[j]);
                    if (!is_t) {
                        int k = atomicAdd(&s_cnt, 1);
                        if (k < CAP) s_cand[k] = x;
                    }
                }
            }
        }
        __syncthreads();
        cnt = min(s_cnt, CAP);
    }

    int n2 = 128;
    while (n2 < cnt) n2 <<= 1;
    for (int i = cnt + tid; i < n2; i += TPB) s_cand[i] = -1e30f;
    __syncthreads();

    for (int k = 2; k <= n2; k <<= 1) {
        for (int j = k >> 1; j > 0; j >>= 1) {
            for (int i = tid; i < n2; i += TPB) {
                int p = i ^ j;
                if (p > i) {
                    float a = s_cand[i], b = s_cand[p];
                    bool asc = ((i & k) == 0);
                    if (asc ? (a > b) : (a < b)) {
                        s_cand[i] = b; s_cand[p] = a;
                    }
                }
            }
            __syncthreads();
        }
    }

    if (tid < 128) {
        float v = (tid < TOPK_) ? s_cand[n2 - 1 - tid] : 0.f;
        s_red[tid] = v;
    }
    __syncthreads();
    #pragma unroll
    for (int off = 64; off > 0; off >>= 1) {
        if (tid < off) s_red[tid] += s_red[tid + off];
        __syncthreads();
    }
    if (tid == 0) atomicAdd(out + 2, s_red[0] * (1.0f / (B_ * TOPK_)));
}

extern "C" void kernel_launch(void* const* d_in, const int* in_sizes, int n_in,
                              void* d_out, int out_size, void* d_ws, size_t ws_size,
                              hipStream_t stream) {
    const float* sparse = (const float*)d_in[0];
    const int*   tids   = (const int*)d_in[1];
    float*       out    = (float*)d_out;

    if (d_ws != nullptr && ws_size >= WS_NEED) {
        float* cand = (float*)d_ws;
        int*   cnt  = (int*)((char*)d_ws + WS_CAND_BYTES);
        // collect zeroes `out` itself (block 0), stream-ordered before select
        collect_kernel<<<B_ * SEG, TPB1, 0, stream>>>(sparse, tids, cand, cnt, out);
        select_kernel<<<B_, TPB2, 0, stream>>>(sparse, tids, cand, cnt, out);
    } else {
        zero_out_kernel<<<1, 1, 0, stream>>>(out);
        row_kernel<<<B_, TPB, 0, stream>>>(sparse, tids, out);
    }
}

// Round 2
// 220.586 us; speedup vs baseline: 1.0063x; 1.0063x over previous
//
#include <hip/hip_runtime.h>
#include <cstddef>
#include <cstdint>

// Problem constants (fixed by reference file)
#define B_    256
#define V_    128000
#define T_    16
#define TOPK_ 100
#define TPB   1024
#define CAP   4096
#define NF4   (V_ / 4)    // 32000 float4 per row
#define NHIST 4096

// Two-phase decomposition
#define SEG    8                   // segments per row
#define CAPSEG 512                 // candidate capacity per segment
#define SEGF4  (NF4 / SEG)         // 4000 float4 per segment
#define TPB1   256                 // collect block size -> 32 waves/CU at 2048 blocks
#define TPB2   512                 // select block size
#define T0     0.996f              // speculative threshold (~512 cand/row expected)

#define FULL_ITERS 15              // SEGF4 = 15*TPB1 + TAIL
#define TAIL       (SEGF4 - FULL_ITERS * TPB1)   // 160

#define WS_CAND_BYTES ((size_t)B_ * SEG * CAPSEG * sizeof(float))   // 4 MiB
#define WS_CNT_BYTES  ((size_t)B_ * SEG * sizeof(int))              // 8 KiB
#define WS_NEED       (WS_CAND_BYTES + WS_CNT_BYTES)

__global__ void zero_out_kernel(float* o) {
    o[0] = 0.f; o[1] = 0.f; o[2] = 0.f;
}

// ---------------------------------------------------------------------------
// Phase 1: full-occupancy streaming scan. 8 blocks per row, each owns a
// contiguous 64 KB segment. Static trip count (15 + 160-lane tail) so the
// compiler keeps multiple loads in flight (#pragma unroll 5 -> 5 deep).
// Candidates >= T0 (excluding target columns) staged in LDS, then written
// contiguously to workspace with a raw count (count > CAPSEG => overflow).
// ---------------------------------------------------------------------------
__global__ __launch_bounds__(TPB1) void collect_kernel(
        const float* __restrict__ sparse,
        const int*   __restrict__ tids,
        float*       __restrict__ cand,   // [B][SEG][CAPSEG]
        int*         __restrict__ cnt,    // [B][SEG]
        float*       __restrict__ out) {
    __shared__ float s_vals[CAPSEG];
    __shared__ int   s_ids[T_];
    __shared__ int   s_cnt;

    const int gb  = blockIdx.x;
    const int row = gb >> 3;         // gb / SEG
    const int seg = gb & 7;          // gb % SEG
    const int tid = threadIdx.x;

    // zero the output accumulators (stream-ordered before select_kernel)
    if (gb == 0 && tid < 3) out[tid] = 0.f;

    if (tid < T_) s_ids[tid] = tids[row * T_ + tid];
    if (tid == 0) s_cnt = 0;
    __syncthreads();

    const float4* __restrict__ rp4 =
        (const float4*)(sparse + (size_t)row * V_) + seg * SEGF4;
    const int colbase = (seg * SEGF4) << 2;

    #pragma unroll 5
    for (int it = 0; it < FULL_ITERS; ++it) {
        const int idx = it * TPB1 + tid;
        float4 v = rp4[idx];
        float mx = fmaxf(fmaxf(v.x, v.y), fmaxf(v.z, v.w));
        if (mx >= T0) {                       // taken ~1.6% of the time
            int col = colbase + (idx << 2);
            float xs[4] = {v.x, v.y, v.z, v.w};
            #pragma unroll
            for (int c = 0; c < 4; ++c) {
                float x = xs[c];
                if (x >= T0) {
                    int cc = col + c;
                    bool is_t = false;
                    #pragma unroll
                    for (int j = 0; j < T_; ++j) is_t |= (cc == s_ids[j]);
                    if (!is_t) {
                        int k = atomicAdd(&s_cnt, 1);
                        if (k < CAPSEG) s_vals[k] = x;
                    }
                }
            }
        }
    }
    if (tid < TAIL) {
        const int idx = FULL_ITERS * TPB1 + tid;
        float4 v = rp4[idx];
        float mx = fmaxf(fmaxf(v.x, v.y), fmaxf(v.z, v.w));
        if (mx >= T0) {
            int col = colbase + (idx << 2);
            float xs[4] = {v.x, v.y, v.z, v.w};
            #pragma unroll
            for (int c = 0; c < 4; ++c) {
                float x = xs[c];
                if (x >= T0) {
                    int cc = col + c;
                    bool is_t = false;
                    #pragma unroll
                    for (int j = 0; j < T_; ++j) is_t |= (cc == s_ids[j]);
                    if (!is_t) {
                        int k = atomicAdd(&s_cnt, 1);
                        if (k < CAPSEG) s_vals[k] = x;
                    }
                }
            }
        }
    }
    __syncthreads();

    int lc = s_cnt;
    int w  = min(lc, CAPSEG);
    float* __restrict__ dst = cand + (size_t)gb * CAPSEG;
    for (int i = tid; i < w; i += TPB1) dst[i] = s_vals[i];
    if (tid == 0) cnt[gb] = lc;      // raw (unclamped) -> overflow detectable
}

// ---------------------------------------------------------------------------
// Phase 2: per-row select. Gathers the ~512 precollected candidates (all 8
// segments concurrently, 64 lanes each), bitonic sorts, sums top-100.
// Computes target/margin losses. Exact histogram fallback if speculation
// failed.
// ---------------------------------------------------------------------------
__global__ __launch_bounds__(TPB2) void select_kernel(
        const float* __restrict__ sparse,
        const int*   __restrict__ tids,
        const float* __restrict__ cand,
        const int*   __restrict__ cnt,
        float*       __restrict__ out) {
    __shared__ float    s_cand[CAP];
    __shared__ unsigned s_hist[NHIST];
    __shared__ int      s_ids[T_];
    __shared__ int      s_scnt[SEG];
    __shared__ int      s_off[SEG + 1];
    __shared__ int      s_flag;
    __shared__ int      s_cnt2;
    __shared__ int      s_bstar;
    __shared__ float    s_red[128];

    const int row = blockIdx.x;
    const int tid = threadIdx.x;
    const float* __restrict__ rp = sparse + (size_t)row * V_;

    if (tid < T_) s_ids[tid] = tids[row * T_ + tid];
    __syncthreads();

    // ---- target loss + margin loss (threads 0..15, one gather each) ----
    if (tid < T_) {
        float x  = rp[s_ids[tid]];
        float tl = -logf(x + 1e-8f);
        float ml = fmaxf(1.0f - x, 0.0f);
        #pragma unroll
        for (int off = 8; off > 0; off >>= 1) {
            tl += __shfl_down(tl, off);
            ml += __shfl_down(ml, off);
        }
        if (tid == 0) {
            atomicAdd(out + 0, tl * (1.0f / (B_ * T_)));
            atomicAdd(out + 1, ml * (1.0f / (B_ * T_)));
        }
    }

    // ---- gather per-segment counts, prefix sum, validate ----
    if (tid == 0) {
        int acc = 0, bad = 0;
        #pragma unroll
        for (int s = 0; s < SEG; ++s) {
            int c = cnt[row * SEG + s];
            bad |= (c > CAPSEG);
            int cc = min(c, CAPSEG);
            s_scnt[s] = cc;
            s_off[s]  = acc;
            acc += cc;
        }
        s_off[SEG] = acc;
        s_flag = bad || (acc < TOPK_) || (acc > CAP);
    }
    __syncthreads();

    int cntv;
    if (!s_flag) {
        // ---- gather candidates into contiguous LDS, 8 segments in parallel
        cntv = s_off[SEG];
        const int sg = tid >> 6;          // 0..7 (TPB2 = 512)
        const int ln = tid & 63;
        const int len = s_scnt[sg];
        const float* __restrict__ src =
            cand + (size_t)(row * SEG + sg) * CAPSEG;
        float* __restrict__ dstp = s_cand + s_off[sg];
        for (int i = ln; i < len; i += 64) dstp[i] = src[i];
        __syncthreads();
    } else {
        // ---- exact fallback: histogram over the full row (proven path) ----
        for (int i = tid; i < NHIST; i += TPB2) s_hist[i] = 0u;
        if (tid == 0) s_cnt2 = 0;
        __syncthreads();
        const float4* rp4 = (const float4*)rp;
        for (int i = tid; i < NF4; i += TPB2) {
            float4 v = rp4[i];
            float xs[4] = {v.x, v.y, v.z, v.w};
            #pragma unroll
            for (int c = 0; c < 4; ++c) {
                int b = (int)(xs[c] * (float)NHIST);
                b = min(max(b, 0), NHIST - 1);
                atomicAdd(&s_hist[b], 1u);
            }
        }
        __syncthreads();
        if (tid == 0) {
            for (int j = 0; j < T_; ++j) {
                int id = s_ids[j];
                bool dup = false;
                for (int q = 0; q < j; ++q) dup = dup || (s_ids[q] == id);
                if (!dup) {
                    int b = (int)(rp[id] * (float)NHIST);
                    b = min(max(b, 0), NHIST - 1);
                    s_hist[b]--;
                }
            }
            int acc = 0, b = NHIST - 1;
            for (; b >= 0; --b) {
                acc += (int)s_hist[b];
                if (acc >= TOPK_) break;
            }
            s_bstar = max(b, 0);
        }
        __syncthreads();
        int bstar = s_bstar;
        for (int i = tid; i < NF4; i += TPB2) {
            float4 v = rp4[i];
            int col = i << 2;
            float xs[4] = {v.x, v.y, v.z, v.w};
            #pragma unroll
            for (int c = 0; c < 4; ++c) {
                float x = xs[c];
                int b2 = (int)(x * (float)NHIST);
                b2 = min(max(b2, 0), NHIST - 1);
                if (b2 >= bstar) {
                    int cc = col + c;
                    bool is_t = false;
                    #pragma unroll
                    for (int j = 0; j < T_; ++j) is_t |= (cc == s_ids[j]);
                    if (!is_t) {
                        int k = atomicAdd(&s_cnt2, 1);
                        if (k < CAP) s_cand[k] = x;
                    }
                }
            }
        }
        __syncthreads();
        cntv = min(s_cnt2, CAP);
    }

    // ---- pad to pow2 and bitonic sort ascending (pads = -inf -> at front) ----
    int n2 = 128;
    while (n2 < cntv) n2 <<= 1;          // n2 <= CAP (pow2)
    for (int i = cntv + tid; i < n2; i += TPB2) s_cand[i] = -1e30f;
    __syncthreads();

    for (int k = 2; k <= n2; k <<= 1) {
        for (int j = k >> 1; j > 0; j >>= 1) {
            for (int i = tid; i < n2; i += TPB2) {
                int p = i ^ j;
                if (p > i) {
                    float a = s_cand[i], b = s_cand[p];
                    bool asc = ((i & k) == 0);
                    if (asc ? (a > b) : (a < b)) {
                        s_cand[i] = b; s_cand[p] = a;
                    }
                }
            }
            __syncthreads();
        }
    }

    // ---- sum the top-100 (largest at the tail after ascending sort) ----
    if (tid < 128) {
        float v = (tid < TOPK_) ? s_cand[n2 - 1 - tid] : 0.f;
        s_red[tid] = v;
    }
    __syncthreads();
    #pragma unroll
    for (int off = 64; off > 0; off >>= 1) {
        if (tid < off) s_red[tid] += s_red[tid + off];
        __syncthreads();
    }
    if (tid == 0) atomicAdd(out + 2, s_red[0] * (1.0f / (B_ * TOPK_)));
}

// ---------------------------------------------------------------------------
// Fallback single-kernel path (previous proven kernel) used only if the
// workspace is too small for the two-phase plan.
// ---------------------------------------------------------------------------
__global__ __launch_bounds__(TPB) void row_kernel(
        const float* __restrict__ sparse,
        const int*   __restrict__ tids,
        float*       __restrict__ out) {
    __shared__ float    s_cand[CAP];
    __shared__ unsigned s_hist[NHIST];
    __shared__ int      s_ids[T_];
    __shared__ int      s_cnt;
    __shared__ int      s_bstar;
    __shared__ float    s_red[128];

    const int row = blockIdx.x;
    const int tid = threadIdx.x;
    const float* __restrict__ rp = sparse + (size_t)row * V_;

    if (tid < T_) s_ids[tid] = tids[row * T_ + tid];
    if (tid == 0) s_cnt = 0;
    __syncthreads();

    if (tid < T_) {
        float x  = rp[s_ids[tid]];
        float tl = -logf(x + 1e-8f);
        float ml = fmaxf(1.0f - x, 0.0f);
        #pragma unroll
        for (int off = 8; off > 0; off >>= 1) {
            tl += __shfl_down(tl, off);
            ml += __shfl_down(ml, off);
        }
        if (tid == 0) {
            atomicAdd(out + 0, tl * (1.0f / (B_ * T_)));
            atomicAdd(out + 1, ml * (1.0f / (B_ * T_)));
        }
    }

    const float4* rp4 = (const float4*)rp;
    for (int i = tid; i < NF4; i += TPB) {
        float4 v = rp4[i];
        int col = i << 2;
        float xs[4] = {v.x, v.y, v.z, v.w};
        #pragma unroll
        for (int c = 0; c < 4; ++c) {
            float x = xs[c];
            if (x >= T0) {
                int cc = col + c;
                bool is_t = false;
                #pragma unroll
                for (int j = 0; j < T_; ++j) is_t |= (cc == s_ids[j]);
                if (!is_t) {
                    int k = atomicAdd(&s_cnt, 1);
                    if (k < CAP) s_cand[k] = x;
                }
            }
        }
    }
    __syncthreads();

    int cnt = s_cnt;
    if (cnt < TOPK_ || cnt > CAP) {
        for (int i = tid; i < NHIST; i += TPB) s_hist[i] = 0u;
        __syncthreads();
        for (int i = tid; i < NF4; i += TPB) {
            float4 v = rp4[i];
            float xs[4] = {v.x, v.y, v.z, v.w};
            #pragma unroll
            for (int c = 0; c < 4; ++c) {
                int b = (int)(xs[c] * (float)NHIST);
                b = min(max(b, 0), NHIST - 1);
                atomicAdd(&s_hist[b], 1u);
            }
        }
        __syncthreads();
        if (tid == 0) {
            for (int j = 0; j < T_; ++j) {
                int id = s_ids[j];
                bool dup = false;
                for (int q = 0; q < j; ++q) dup = dup || (s_ids[q] == id);
                if (!dup) {
                    int b = (int)(rp[id] * (float)NHIST);
                    b = min(max(b, 0), NHIST - 1);
                    s_hist[b]--;
                }
            }
            int acc = 0, b = NHIST - 1;
            for (; b >= 0; --b) {
                acc += (int)s_hist[b];
                if (acc >= TOPK_) break;
            }
            s_bstar = max(b, 0);
            s_cnt = 0;
        }
        __syncthreads();
        int bstar = s_bstar;
        for (int i = tid; i < NF4; i += TPB) {
            float4 v = rp4[i];
            int col = i << 2;
            float xs[4] = {v.x, v.y, v.z, v.w};
            #pragma unroll
            for (int c = 0; c < 4; ++c) {
                float x = xs[c];
                int b = (int)(x * (float)NHIST);
                b = min(max(b, 0), NHIST - 1);
                if (b >= bstar) {
                    int cc = col + c;
                    bool is_t = false;
                    #pragma unroll
                    for (int j = 0; j < T_; ++j) is_t |= (cc == s_ids[j]);
                    if (!is_t) {
                        int k = atomicAdd(&s_cnt, 1);
                        if (k < CAP) s_cand[k] = x;
                    }
                }
            }
        }
        __syncthreads();
        cnt = min(s_cnt, CAP);
    }

    int n2 = 128;
    while (n2 < cnt) n2 <<= 1;
    for (int i = cnt + tid; i < n2; i += TPB) s_cand[i] = -1e30f;
    __syncthreads();

    for (int k = 2; k <= n2; k <<= 1) {
        for (int j = k >> 1; j > 0; j >>= 1) {
            for (int i = tid; i < n2; i += TPB) {
                int p = i ^ j;
                if (p > i) {
                    float a = s_cand[i], b = s_cand[p];
                    bool asc = ((i & k) == 0);
                    if (asc ? (a > b) : (a < b)) {
                        s_cand[i] = b; s_cand[p] = a;
                    }
                }
            }
            __syncthreads();
        }
    }

    if (tid < 128) {
        float v = (tid < TOPK_) ? s_cand[n2 - 1 - tid] : 0.f;
        s_red[tid] = v;
    }
    __syncthreads();
    #pragma unroll
    for (int off = 64; off > 0; off >>= 1) {
        if (tid < off) s_red[tid] += s_red[tid + off];
        __syncthreads();
    }
    if (tid == 0) atomicAdd(out + 2, s_red[0] * (1.0f / (B_ * TOPK_)));
}

extern "C" void kernel_launch(void* const* d_in, const int* in_sizes, int n_in,
                              void* d_out, int out_size, void* d_ws, size_t ws_size,
                              hipStream_t stream) {
    const float* sparse = (const float*)d_in[0];
    const int*   tids   = (const int*)d_in[1];
    float*       out    = (float*)d_out;

    if (d_ws != nullptr && ws_size >= WS_NEED) {
        float* cand = (float*)d_ws;
        int*   cnt  = (int*)((char*)d_ws + WS_CAND_BYTES);
        // collect zeroes `out` itself (block 0), stream-ordered before select
        collect_kernel<<<B_ * SEG, TPB1, 0, stream>>>(sparse, tids, cand, cnt, out);
        select_kernel<<<B_, TPB2, 0, stream>>>(sparse, tids, cand, cnt, out);
    } else {
        zero_out_kernel<<<1, 1, 0, stream>>>(out);
        row_kernel<<<B_, TPB, 0, stream>>>(sparse, tids, out);
    }
}